// Round 1
// baseline (1255.313 us; speedup 1.0000x reference)
//
#include <hip/hip_runtime.h>

// Problem constants
#define PAD_ID 0
#define NTOK   16384          // B*L = 16*1024
#define DIM    768
#define KLAT   5000
#define KPAD   5024           // 157*32, zero-padded latent rows
#define NSTEP  157            // ceil(5000/32)

typedef float f32x4 __attribute__((ext_vector_type(4)));
typedef __bf16 bf16x8 __attribute__((ext_vector_type(8)));
typedef unsigned short ushort8v __attribute__((ext_vector_type(8)));

__device__ __forceinline__ unsigned short f2bf(float f) {
    unsigned int u = __float_as_uint(f);
    u += 0x7fffu + ((u >> 16) & 1u);   // RNE
    return (unsigned short)(u >> 16);
}
__device__ __forceinline__ float bf2f(unsigned short h) {
    return __uint_as_float(((unsigned int)h) << 16);
}

// ---------------------------------------------------------------------------
// Kernel 0: latent_mat fp32 -> bf16 copy, zero-padded to KPAD rows.
// ---------------------------------------------------------------------------
__global__ __launch_bounds__(256) void cvt_latent(const float* __restrict__ latent,
                                                  unsigned short* __restrict__ latb) {
    int idx4 = blockIdx.x * 256 + threadIdx.x;      // each thread: 4 elems
    long e0 = (long)idx4 * 4;
    if (e0 >= (long)KPAD * DIM) return;
    int row = (int)(e0 / DIM);                      // 768 % 4 == 0 -> uniform row
    float4 v = make_float4(0.f, 0.f, 0.f, 0.f);
    if (row < KLAT) v = *(const float4*)(latent + e0);
    unsigned int u0 = (unsigned int)f2bf(v.x) | ((unsigned int)f2bf(v.y) << 16);
    unsigned int u1 = (unsigned int)f2bf(v.z) | ((unsigned int)f2bf(v.w) << 16);
    *(uint2*)(latb + e0) = make_uint2(u0, u1);
}

// ---------------------------------------------------------------------------
// Kernel 1: lang_emb = tanh(masked-mean of char embeddings), stored bf16.
// One block per token, 192 threads x float4 = 768 dims.
// ---------------------------------------------------------------------------
__global__ __launch_bounds__(192) void build_lang(const int* __restrict__ x,
                                                  const float* __restrict__ cemb,
                                                  unsigned short* __restrict__ langb) {
    int tok = blockIdx.x;
    int t = threadIdx.x;
    const int* xs = x + tok * 8;
    int ids[8]; int cnt = 0;
    #pragma unroll
    for (int c = 0; c < 8; ++c) { ids[c] = xs[c]; cnt += (ids[c] != PAD_ID); }
    float4 acc = make_float4(0.f, 0.f, 0.f, 0.f);
    #pragma unroll
    for (int c = 0; c < 8; ++c) {
        if (ids[c] != PAD_ID) {
            float4 v = *(const float4*)(cemb + (long)ids[c] * DIM + t * 4);
            acc.x += v.x; acc.y += v.y; acc.z += v.z; acc.w += v.w;
        }
    }
    float cntf = (float)max(cnt, 1);
    unsigned int u0 = (unsigned int)f2bf(tanhf(acc.x / cntf)) |
                      ((unsigned int)f2bf(tanhf(acc.y / cntf)) << 16);
    unsigned int u1 = (unsigned int)f2bf(tanhf(acc.z / cntf)) |
                      ((unsigned int)f2bf(tanhf(acc.w / cntf)) << 16);
    *(uint2*)(langb + tok * DIM + t * 4) = make_uint2(u0, u1);
}

// ---------------------------------------------------------------------------
// Kernel 2: fused scores -> softmax (no max-sub; scores are O(1)) -> P@Lat
//           -> /l + lang_emb + special-token override -> out.
// Grid: 256 blocks x 64 tokens. 256 threads (4 waves), wave w owns
// token-tile w (16 tokens, Q frags in regs) and D-slice [w*192, w*192+192).
// Per k-step (32 latents): stage Lat tile (bf16, padded rows) to LDS,
// S^T = Lat*Q^T via mfma 16x16x32 (A=Lat rows b128, B=Q regs), exp in
// C-layout regs -> P to LDS, O += P*Lat (B-frags strided u16 from sLat).
// ---------------------------------------------------------------------------
__global__ __launch_bounds__(256, 1) void fused_sde(
        const int* __restrict__ x, const float* __restrict__ cemb,
        const unsigned short* __restrict__ langb,
        const unsigned short* __restrict__ latb,
        float* __restrict__ out) {
    // LDS: 32x(768+8) lat tile + 64x(32+8) P + 64 l  = 55 KB (< 64 KB static cap)
    __shared__ unsigned short sLat[32 * 776];
    __shared__ unsigned short sP[64 * 40];
    __shared__ float sL[64];

    const int tid  = threadIdx.x;
    const int w    = tid >> 6;        // wave 0..3
    const int lane = tid & 63;
    const int ln   = lane & 15;
    const int quad = lane >> 4;
    const int m0   = blockIdx.x * 64;

    // Q fragments (B-operand for S^T): token = m0 + w*16 + ln, full K=768
    uint4 qf[24];
    {
        const unsigned short* qr = langb + (m0 + w * 16 + ln) * DIM;
        #pragma unroll
        for (int kf = 0; kf < 24; ++kf)
            qf[kf] = *(const uint4*)(qr + kf * 32 + quad * 8);
    }

    f32x4 accO[4][12];
    #pragma unroll
    for (int mt = 0; mt < 4; ++mt)
        #pragma unroll
        for (int dt = 0; dt < 12; ++dt)
            accO[mt][dt] = (f32x4){0.f, 0.f, 0.f, 0.f};

    float lpart = 0.f;

    // Prefetch tile 0 into registers
    uint4 pf[12];
    #pragma unroll
    for (int i = 0; i < 12; ++i)
        pf[i] = *(const uint4*)(latb + (i * 256 + tid) * 8);

    for (int step = 0; step < NSTEP; ++step) {
        const int k0 = step * 32;
        __syncthreads();                       // prev O-phase done with sLat/sP
        // write staged tile (row-padded)
        #pragma unroll
        for (int i = 0; i < 12; ++i) {
            int idx = i * 256 + tid;
            int row = idx / 96, c8 = idx % 96;
            *(uint4*)&sLat[row * 776 + c8 * 8] = pf[i];
        }
        // prefetch next tile (overlaps with this step's compute)
        {
            int nk0 = (step + 1 < NSTEP) ? (k0 + 32) : 0;
            #pragma unroll
            for (int i = 0; i < 12; ++i)
                pf[i] = *(const uint4*)(latb + nk0 * 768 + (i * 256 + tid) * 8);
        }
        __syncthreads();                       // sLat ready

        // ---- S^T phase: D[lat][tok], A = Lat tile, B = Q regs ----
        f32x4 s0 = {0.f, 0.f, 0.f, 0.f}, s1 = {0.f, 0.f, 0.f, 0.f};
        #pragma unroll
        for (int kf = 0; kf < 24; ++kf) {
            bf16x8 a0 = *(const bf16x8*)&sLat[ln * 776 + kf * 32 + quad * 8];
            bf16x8 a1 = *(const bf16x8*)&sLat[(16 + ln) * 776 + kf * 32 + quad * 8];
            bf16x8 b  = *(const bf16x8*)&qf[kf];
            s0 = __builtin_amdgcn_mfma_f32_16x16x32_bf16(a0, b, s0, 0, 0, 0);
            s1 = __builtin_amdgcn_mfma_f32_16x16x32_bf16(a1, b, s1, 0, 0, 0);
        }
        // ---- exp (no max-sub), P write, l partial (lane's token = w*16+ln) ----
        {
            unsigned short* prow = &sP[(w * 16 + ln) * 40];
            #pragma unroll
            for (int r = 0; r < 4; ++r) {
                int lat0 = k0 + quad * 4 + r;
                float e0 = (lat0 < KLAT) ? __expf(s0[r]) : 0.f;
                float e1 = (lat0 + 16 < KLAT) ? __expf(s1[r]) : 0.f;
                lpart += e0 + e1;
                prow[quad * 4 + r]      = f2bf(e0);
                prow[16 + quad * 4 + r] = f2bf(e1);
            }
        }
        __syncthreads();                       // sP ready (sLat still live)

        // ---- O phase: O[tok][d] += P[tok][lat] * Lat[lat][d] ----
        bf16x8 pA[4];
        #pragma unroll
        for (int mt = 0; mt < 4; ++mt)
            pA[mt] = *(const bf16x8*)&sP[(mt * 16 + ln) * 40 + quad * 8];
        #pragma unroll
        for (int dt = 0; dt < 12; ++dt) {
            int col = w * 192 + dt * 16 + ln;
            ushort8v bv;
            #pragma unroll
            for (int j = 0; j < 8; ++j)
                bv[j] = sLat[(quad * 8 + j) * 776 + col];
            bf16x8 b = *(const bf16x8*)&bv;
            #pragma unroll
            for (int mt = 0; mt < 4; ++mt)
                accO[mt][dt] = __builtin_amdgcn_mfma_f32_16x16x32_bf16(
                    pA[mt], b, accO[mt][dt], 0, 0, 0);
        }
    }

    // final softmax denominator: reduce 4 quads (token preserved under xor 16/32)
    lpart += __shfl_xor(lpart, 16, 64);
    lpart += __shfl_xor(lpart, 32, 64);
    if (lane < 16) sL[w * 16 + lane] = lpart;
    __syncthreads();

    // epilogue: /l + lang + special-token override, write fp32
    #pragma unroll
    for (int mt = 0; mt < 4; ++mt) {
        int tl0 = mt * 16 + quad * 4;
        float linv[4]; int fid[4];
        #pragma unroll
        for (int r = 0; r < 4; ++r) {
            linv[r] = 1.0f / sL[tl0 + r];
            fid[r]  = x[(m0 + tl0 + r) * 8];
        }
        #pragma unroll
        for (int dt = 0; dt < 12; ++dt) {
            int d = w * 192 + dt * 16 + ln;
            #pragma unroll
            for (int r = 0; r < 4; ++r) {
                int tok = m0 + tl0 + r;
                float v = accO[mt][dt][r] * linv[r] + bf2f(langb[tok * DIM + d]);
                if (fid[r] < 4) v = cemb[fid[r] * DIM + d];  // PAD/CLS/SEP/UNK
                out[tok * DIM + d] = v;
            }
        }
    }
}

// ---------------------------------------------------------------------------
extern "C" void kernel_launch(void* const* d_in, const int* in_sizes, int n_in,
                              void* d_out, int out_size, void* d_ws, size_t ws_size,
                              hipStream_t stream) {
    const int*   x      = (const int*)d_in[0];     // (16,1024,8) int
    const float* cemb   = (const float*)d_in[1];   // (30000,768) f32
    const float* latent = (const float*)d_in[2];   // (5000,768) f32
    float* out = (float*)d_out;                    // (16,1024,768) f32

    unsigned short* langb = (unsigned short*)d_ws;                       // 25.2 MB
    unsigned short* latb  = (unsigned short*)((char*)d_ws +
                              (size_t)NTOK * DIM * 2);                   // 7.7 MB

    cvt_latent<<<(KPAD * DIM / 4 + 255) / 256, 256, 0, stream>>>(latent, latb);
    build_lang<<<NTOK, 192, 0, stream>>>(x, cemb, langb);
    fused_sde<<<NTOK / 64, 256, 0, stream>>>(x, cemb, langb, latb, out);
}

// Round 2
// 582.233 us; speedup vs baseline: 2.1560x; 2.1560x over previous
//
#include <hip/hip_runtime.h>

// Problem constants
#define PAD_ID 0
#define NTOK   16384          // B*L = 16*1024
#define DIM    768
#define KLAT   5000
#define KPAD   5024           // 157*32, zero-padded latent rows
#define NSTEP  157            // 5024/32
#define TILE_SH 24576         // shorts per 32x768 tile (48 KB)

typedef float f32x4 __attribute__((ext_vector_type(4)));
typedef __bf16 bf16x8 __attribute__((ext_vector_type(8)));

__device__ __forceinline__ unsigned short f2bf(float f) {
    unsigned int u = __float_as_uint(f);
    u += 0x7fffu + ((u >> 16) & 1u);   // RNE
    return (unsigned short)(u >> 16);
}
__device__ __forceinline__ float bf2f(unsigned short h) {
    return __uint_as_float(((unsigned int)h) << 16);
}
__device__ __forceinline__ void async_cp16(const unsigned short* g, unsigned short* l) {
    __builtin_amdgcn_global_load_lds(
        (const __attribute__((address_space(1))) unsigned int*)g,
        (__attribute__((address_space(3))) unsigned int*)l, 16, 0, 0);
}

// ---------------------------------------------------------------------------
// Kernel 0a: latent -> latbS, bf16, MFMA-A-fragment order per 32-row tile:
//   latbS[t][kf][h][lane][j] = Lat[t*32 + h*16 + (lane&15)][kf*32 + (lane>>4)*8 + j]
// S-phase LDS image is then frag-linear: ds_read_b128 at stride-1, 0 conflicts.
// ---------------------------------------------------------------------------
__global__ __launch_bounds__(256) void cvt_latS(const float* __restrict__ latent,
                                                unsigned short* __restrict__ latbS) {
    int g = blockIdx.x * 256 + threadIdx.x;          // one 8-short frag per thread
    if (g >= NSTEP * 24 * 2 * 64) return;
    int lane = g & 63; int rest = g >> 6;            // [t][kf][h]
    int h = rest & 1;  int kfr = rest >> 1;
    int kf = kfr % 24; int t  = kfr / 24;
    int row = t * 32 + h * 16 + (lane & 15);
    int col = kf * 32 + (lane >> 4) * 8;
    float4 v0 = make_float4(0.f,0.f,0.f,0.f), v1 = v0;
    if (row < KLAT) {
        v0 = *(const float4*)(latent + (long)row * DIM + col);
        v1 = *(const float4*)(latent + (long)row * DIM + col + 4);
    }
    uint4 o;
    o.x = (unsigned)f2bf(v0.x) | ((unsigned)f2bf(v0.y) << 16);
    o.y = (unsigned)f2bf(v0.z) | ((unsigned)f2bf(v0.w) << 16);
    o.z = (unsigned)f2bf(v1.x) | ((unsigned)f2bf(v1.y) << 16);
    o.w = (unsigned)f2bf(v1.z) | ((unsigned)f2bf(v1.w) << 16);
    *(uint4*)(latbS + (size_t)g * 8) = o;
}

// ---------------------------------------------------------------------------
// Kernel 0b: latent -> latbT, bf16, d-major per tile:
//   latbT[t][d][kk] = Lat[t*32 + kk][d]   (tile = 768x32 = 48 KB)
// O-phase B-frags become fully-coalesced global dwordx4 direct to registers.
// ---------------------------------------------------------------------------
__global__ __launch_bounds__(256) void cvt_latT(const float* __restrict__ latent,
                                                unsigned short* __restrict__ latbT) {
    int g = blockIdx.x * 256 + threadIdx.x;          // one 8-short group
    if (g >= NSTEP * DIM * 4) return;
    int kk8 = g & 3; int rest = g >> 2;
    int d = rest % DIM; int t = rest / DIM;
    int kk0 = kk8 * 8;
    unsigned short v[8];
    #pragma unroll
    for (int j = 0; j < 8; ++j) {
        int row = t * 32 + kk0 + j;
        v[j] = (row < KLAT) ? f2bf(latent[(long)row * DIM + d]) : (unsigned short)0;
    }
    *(uint4*)(latbT + (size_t)g * 8) = *(uint4*)v;
}

// ---------------------------------------------------------------------------
// Kernel 1: lang_emb = tanh(masked-mean of char embeddings), stored bf16.
// ---------------------------------------------------------------------------
__global__ __launch_bounds__(192) void build_lang(const int* __restrict__ x,
                                                  const float* __restrict__ cemb,
                                                  unsigned short* __restrict__ langb) {
    int tok = blockIdx.x;
    int t = threadIdx.x;
    const int* xs = x + tok * 8;
    int ids[8]; int cnt = 0;
    #pragma unroll
    for (int c = 0; c < 8; ++c) { ids[c] = xs[c]; cnt += (ids[c] != PAD_ID); }
    float4 acc = make_float4(0.f, 0.f, 0.f, 0.f);
    #pragma unroll
    for (int c = 0; c < 8; ++c) {
        if (ids[c] != PAD_ID) {
            float4 v = *(const float4*)(cemb + (long)ids[c] * DIM + t * 4);
            acc.x += v.x; acc.y += v.y; acc.z += v.z; acc.w += v.w;
        }
    }
    float cntf = (float)max(cnt, 1);
    unsigned int u0 = (unsigned int)f2bf(tanhf(acc.x / cntf)) |
                      ((unsigned int)f2bf(tanhf(acc.y / cntf)) << 16);
    unsigned int u1 = (unsigned int)f2bf(tanhf(acc.z / cntf)) |
                      ((unsigned int)f2bf(tanhf(acc.w / cntf)) << 16);
    *(uint2*)(langb + tok * DIM + t * 4) = make_uint2(u0, u1);
}

// ---------------------------------------------------------------------------
// Kernel 2: fused scores -> softmax (no max-sub; |s| = O(1)) -> P@Lat
//           -> /l + lang_emb + special-token override -> out.
// 256 blocks x 64 tokens, 4 waves. Q frags persistent in regs.
// Per step: S^T via mfma from frag-linear sLat (ds_read_b128, 0-conflict);
// exp -> sP; barrier; global_load_lds DMA of tile s+1 (hidden under O-phase);
// O-phase B-frags direct from latbT (global, coalesced); barrier drains DMA.
// ---------------------------------------------------------------------------
__global__ __launch_bounds__(256, 1) void fused_sde(
        const int* __restrict__ x, const float* __restrict__ cemb,
        const unsigned short* __restrict__ langb,
        const unsigned short* __restrict__ latbS,
        const unsigned short* __restrict__ latbT,
        float* __restrict__ out) {
    __shared__ unsigned short sLat[TILE_SH];   // 48 KB, frag-linear image
    __shared__ unsigned short sP[64 * 40];     // P, row-padded (+8) for banks
    __shared__ float sL[64];

    const int tid  = threadIdx.x;
    const int w    = tid >> 6;
    const int lane = tid & 63;
    const int ln   = lane & 15;
    const int quad = lane >> 4;
    const int m0   = blockIdx.x * 64;

    // Q fragments (B-operand for S^T): token = m0 + w*16 + ln
    uint4 qf[24];
    {
        const unsigned short* qr = langb + (m0 + w * 16 + ln) * DIM;
        #pragma unroll
        for (int kf = 0; kf < 24; ++kf)
            qf[kf] = *(const uint4*)(qr + kf * 32 + quad * 8);
    }

    f32x4 accO[4][12];
    #pragma unroll
    for (int mt = 0; mt < 4; ++mt)
        #pragma unroll
        for (int dt = 0; dt < 12; ++dt)
            accO[mt][dt] = (f32x4){0.f, 0.f, 0.f, 0.f};
    float lpart = 0.f;

    // Prologue: DMA tile 0 into LDS
    #pragma unroll
    for (int i = 0; i < 12; ++i)
        async_cp16(latbS + ((size_t)i * 256 + tid) * 8,
                   sLat + (i * 256 + (tid & ~63)) * 8);
    __syncthreads();   // drain -> tile 0 ready

    for (int s = 0; s < NSTEP; ++s) {
        // Prefetch O-phase B frags for THIS step (global -> regs, coalesced 1KB/wave)
        uint4 bO[12];
        {
            const unsigned short* bt = latbT + (size_t)s * TILE_SH;
            #pragma unroll
            for (int dt = 0; dt < 12; ++dt)
                bO[dt] = *(const uint4*)(bt + (w * 192 + dt * 16 + ln) * 32 + quad * 8);
        }

        // ---- S^T phase: frag-linear LDS reads, zero conflicts ----
        f32x4 s0 = {0.f,0.f,0.f,0.f}, s1 = {0.f,0.f,0.f,0.f};
        #pragma unroll
        for (int kf = 0; kf < 24; ++kf) {
            bf16x8 a0 = *(const bf16x8*)&sLat[(kf * 128 + lane) * 8];
            bf16x8 a1 = *(const bf16x8*)&sLat[(kf * 128 + 64 + lane) * 8];
            bf16x8 b  = *(const bf16x8*)&qf[kf];
            s0 = __builtin_amdgcn_mfma_f32_16x16x32_bf16(a0, b, s0, 0, 0, 0);
            s1 = __builtin_amdgcn_mfma_f32_16x16x32_bf16(a1, b, s1, 0, 0, 0);
        }

        // ---- exp (no max-sub), P write, l partial ----
        {
            const int k0 = s * 32;
            unsigned short* prow = &sP[(w * 16 + ln) * 40];
            #pragma unroll
            for (int r = 0; r < 4; ++r) {
                int lat0 = k0 + quad * 4 + r;
                float e0 = (lat0 < KLAT) ? __expf(s0[r]) : 0.f;
                float e1 = (lat0 + 16 < KLAT) ? __expf(s1[r]) : 0.f;
                lpart += e0 + e1;
                prow[quad * 4 + r]      = f2bf(e0);
                prow[16 + quad * 4 + r] = f2bf(e1);
            }
        }
        __syncthreads();   // S-reads of sLat done; sP published

        // DMA next tile into sLat (drained at loop-end barrier, hidden by O-phase)
        {
            int nt = (s + 1 < NSTEP) ? s + 1 : 0;
            const unsigned short* gs = latbS + (size_t)nt * TILE_SH;
            #pragma unroll
            for (int i = 0; i < 12; ++i)
                async_cp16(gs + (i * 256 + tid) * 8,
                           sLat + (i * 256 + (tid & ~63)) * 8);
        }

        // ---- O phase: O[tok][d] += P[tok][lat] * Lat[lat][d] ----
        bf16x8 pA[4];
        #pragma unroll
        for (int mt = 0; mt < 4; ++mt)
            pA[mt] = *(const bf16x8*)&sP[(mt * 16 + ln) * 40 + quad * 8];
        #pragma unroll
        for (int dt = 0; dt < 12; ++dt) {
            bf16x8 b = *(const bf16x8*)&bO[dt];
            #pragma unroll
            for (int mt = 0; mt < 4; ++mt)
                accO[mt][dt] = __builtin_amdgcn_mfma_f32_16x16x32_bf16(
                    pA[mt], b, accO[mt][dt], 0, 0, 0);
        }
        __syncthreads();   // drains DMA (tile s+1 ready); sP reads done
    }

    // softmax denominator: reduce over quads (token invariant under xor 16/32)
    lpart += __shfl_xor(lpart, 16, 64);
    lpart += __shfl_xor(lpart, 32, 64);
    if (lane < 16) sL[w * 16 + lane] = lpart;
    __syncthreads();

    // epilogue: /l + lang + special-token override, fp32 out
    #pragma unroll
    for (int mt = 0; mt < 4; ++mt) {
        int tl0 = mt * 16 + quad * 4;
        float linv[4]; int fid[4];
        #pragma unroll
        for (int r = 0; r < 4; ++r) {
            linv[r] = 1.0f / sL[tl0 + r];
            fid[r]  = x[(m0 + tl0 + r) * 8];
        }
        #pragma unroll
        for (int dt = 0; dt < 12; ++dt) {
            int d = w * 192 + dt * 16 + ln;
            #pragma unroll
            for (int r = 0; r < 4; ++r) {
                int tok = m0 + tl0 + r;
                float v = accO[mt][dt][r] * linv[r] + bf2f(langb[tok * DIM + d]);
                if (fid[r] < 4) v = cemb[fid[r] * DIM + d];  // PAD/CLS/SEP/UNK
                out[tok * DIM + d] = v;
            }
        }
    }
}

// ---------------------------------------------------------------------------
extern "C" void kernel_launch(void* const* d_in, const int* in_sizes, int n_in,
                              void* d_out, int out_size, void* d_ws, size_t ws_size,
                              hipStream_t stream) {
    const int*   x      = (const int*)d_in[0];     // (16,1024,8) int
    const float* cemb   = (const float*)d_in[1];   // (30000,768) f32
    const float* latent = (const float*)d_in[2];   // (5000,768) f32
    float* out = (float*)d_out;                    // (16,1024,768) f32

    unsigned short* langb = (unsigned short*)d_ws;                          // 25.2 MB
    unsigned short* latbS = langb + (size_t)NTOK * DIM;                     // 7.7 MB
    unsigned short* latbT = latbS + (size_t)NSTEP * TILE_SH;                // 7.7 MB

    int nS = NSTEP * 24 * 2 * 64;        // frag groups in latbS
    int nT = NSTEP * DIM * 4;            // 8-short groups in latbT
    cvt_latS<<<(nS + 255) / 256, 256, 0, stream>>>(latent, latbS);
    cvt_latT<<<(nT + 255) / 256, 256, 0, stream>>>(latent, latbT);
    build_lang<<<NTOK, 192, 0, stream>>>(x, cemb, langb);
    fused_sde<<<NTOK / 64, 256, 0, stream>>>(x, cemb, langb, latbS, latbT, out);
}